// Round 14
// baseline (70.022 us; speedup 1.0000x reference)
//
#include <hip/hip_runtime.h>
#include <hip/hip_bf16.h>

typedef __bf16 bf16x8 __attribute__((ext_vector_type(8)));
typedef float f32x4 __attribute__((ext_vector_type(4)));
typedef float f32x16 __attribute__((ext_vector_type(16)));

#define B_N 2048
#define O_N 2048
#define K_TRI 2080
#define K_TOT 2304
#define K_STEPS 36                 // per K-half: 36 steps x K=32
#define STEP_B 131072              // 4 chunks * 2048 rows * 16B

__device__ __forceinline__ void gld16(const void* g, void* l) {
    __builtin_amdgcn_global_load_lds(
        (const __attribute__((address_space(1))) void*)g,
        (__attribute__((address_space(3))) void*)l,
        16, 0, 0);
}

// ---------------------------------------------------------------------------
// prep A (R13-proven): blocks [0,2048): S rows ROW-MAJOR per o;
//   blocks [2048,2304): P rows directly TILED (8 b-rows, full-line writes).
// ---------------------------------------------------------------------------
__global__ __launch_bounds__(256) void rbf_prepA(
    const float* __restrict__ inv, const float* __restrict__ means,
    const float* __restrict__ x, __bf16* __restrict__ Srm,
    __bf16* __restrict__ Pt)
{
    __shared__ float s[64 * 65];
    __shared__ float mld[64];
    __shared__ float uw[128];
    __shared__ unsigned short ptab[K_TRI];

    const int t = threadIdx.x;
    {
        int base = 0;
#pragma unroll 1
        for (int i = 0; i < 64; ++i) {
            if (t < 64 - i) ptab[base + t] = (unsigned short)((i << 8) | (i + t));
            base += 64 - i;
        }
    }

    if ((int)blockIdx.x < O_N) {
        const int o = blockIdx.x;
        const float4* src = (const float4*)(inv + (size_t)o * 4096);
#pragma unroll
        for (int k = 0; k < 4; ++k) {
            const int idx = k * 256 + t;
            const float4 v = src[idx];
            const int i = idx >> 4;
            const int j0 = (idx & 15) * 4;
            s[i * 65 + j0 + 0] = v.x * v.x;
            s[i * 65 + j0 + 1] = v.y * v.y;
            s[i * 65 + j0 + 2] = v.z * v.z;
            s[i * 65 + j0 + 3] = v.w * v.w;
        }
        if (t < 64) mld[t] = means[(size_t)t * O_N + o];
        __syncthreads();
        if (t < 64) {
            float u = 0.f;
#pragma unroll
            for (int i = 0; i < 64; ++i) u = fmaf(s[i * 65 + t], mld[i], u);
            uw[t] = u;
        } else if (t < 128) {
            const int j = t - 64;
            float w = 0.f;
#pragma unroll
            for (int i = 0; i < 64; ++i) w = fmaf(s[j * 65 + i], mld[i], w);
            uw[64 + j] = w;
        }
        __syncthreads();
        __bf16* Srow = Srm + (size_t)o * K_TOT;
#pragma unroll 1
        for (int c = t; c < K_TOT; c += 256) {
            float v;
            if (c < K_TRI) {
                const int ij = ptab[c];
                const int i = ij >> 8, j = ij & 255;
                v = (i == j) ? s[i * 65 + i] : (s[i * 65 + j] + s[j * 65 + i]);
            } else if (c < 2272) {
                const int j = (c - K_TRI) & 63;
                const float cv = -(uw[j] + uw[64 + j]);
                const __bf16 hi = (__bf16)cv;
                v = (c < 2208) ? (float)hi : (cv - (float)hi);
            } else if (c < 2274) {
                float kk = 0.f;
#pragma unroll
                for (int j = 0; j < 64; ++j) kk = fmaf(uw[j], mld[j], kk);
                const __bf16 khi = (__bf16)kk;
                v = (c == 2272) ? (float)khi : (kk - (float)khi);
            } else v = 0.f;
            Srow[c] = (__bf16)v;
        }
    } else {
        const int b0r = ((int)blockIdx.x - O_N) * 8;
#pragma unroll
        for (int q = 0; q < 2; ++q) {
            const int idx = q * 256 + t;
            s[(idx >> 6) * 65 + (idx & 63)] =
                x[(size_t)(b0r + (idx >> 6)) * 64 + (idx & 63)];
        }
        __syncthreads();
#pragma unroll 1
        for (int q = 0; q < 9; ++q) {
            const int task = q * 256 + t;
            const int c8 = task >> 3, r8 = task & 7;
            const float* xr = &s[r8 * 65];
            unsigned short w8[8];
#pragma unroll
            for (int e = 0; e < 8; ++e) {
                const int c = c8 * 8 + e;
                float v;
                if (c < K_TRI) {
                    const int ij = ptab[c];
                    v = xr[ij >> 8] * xr[ij & 255];
                } else if (c < 2272) {
                    const float xv = xr[(c - K_TRI) & 63];
                    const __bf16 hi = (__bf16)xv;
                    v = (c < 2144) ? (float)hi
                      : (c < 2208) ? (xv - (float)hi) : (float)hi;
                } else if (c < 2274) v = 1.f;
                else v = 0.f;
                w8[e] = __builtin_bit_cast(unsigned short, (__bf16)v);
            }
            *(bf16x8*)(Pt + ((size_t)c8 * 2048 + b0r + r8) * 8) =
                *(const bf16x8*)w8;
        }
    }
}

// ---------------------------------------------------------------------------
// prep B (R13-proven): transpose Srm -> St tiled [chunk][row][16B].
// ---------------------------------------------------------------------------
__global__ __launch_bounds__(256, 2) void rbf_prepB(
    const __bf16* __restrict__ Srm, __bf16* __restrict__ St)
{
    __shared__ __align__(16) char ts[64 * 1156];
    const int t = threadIdx.x;
    const int tb = (int)blockIdx.x >> 2;
    const int cp = (int)blockIdx.x & 3;
    const int o0 = tb * 64;

#pragma unroll 1
    for (int q = 0; q < 18; ++q) {
        const int idx = q * 256 + t;
        const int r = idx / 72, c = idx % 72;
        const float4 v = *(const float4*)((const char*)Srm
                          + (size_t)(o0 + r) * (K_TOT * 2) + cp * 1152 + c * 16);
        *(float4*)(&ts[r * 1156 + c * 16]) = v;
    }
    __syncthreads();
#pragma unroll 1
    for (int q = 0; q < 18; ++q) {
        const int idx = q * 256 + t;
        const int c = idx >> 6, r = idx & 63;
        const float4 v = *(const float4*)(&ts[r * 1156 + c * 16]);
        *(float4*)((char*)St + ((size_t)(cp * 72 + c) * 2048 + o0 + r) * 16) = v;
    }
}

// ---------------------------------------------------------------------------
// GEMM split-K: 512 blocks = 256 tiles (128x128) x 2 K-halves (K=1152 each).
// 2 blocks/CU (LDS 64KB), 2 waves/SIMD TLP. 4 waves x 64x64; per step (K=32):
// 4 gld16/thread (contiguous 2KB rounds), 8 ds_read_b128 + 8 MFMA per wave,
// ONE barrier, counted vmcnt(8)/(4)/(0) - R12's proven ordering, scaled.
// Writes f32 partial tile to Cpart[kh] (no epilogue math).
// C-layout (32x32): col = lane&31, row = (r&3)+8*(r>>2)+4*(lane>>5).
// ---------------------------------------------------------------------------
__global__ __launch_bounds__(256, 2) void rbf_gemm_sk(
    const __bf16* __restrict__ P, const __bf16* __restrict__ S,
    float* __restrict__ Cpart)
{
    __shared__ __align__(16) char sAB[4][16384];

    const int tid = threadIdx.x;
    const int lane = tid & 63;
    const int w = tid >> 6;
    const int wr = w >> 1, wc = w & 1;
    const int cl = lane & 31;
    const int h = lane >> 5;

    // 512 = 8 XCD x (16 bpan x 2 opan x 2 kh); per-XCD S slice 1.18MB
    const int wg = (int)blockIdx.x;
    const int xcd = wg & 7;
    const int loc = wg >> 3;               // 0..63
    const int kh = loc & 1;
    const int opan = (loc >> 1) & 1;
    const int bpan = loc >> 2;             // 0..15
    const int oBase = (xcd * 2 + opan) * 128;
    const int bBase = bpan * 128;
    const int kc = kh * 144;               // chunk base of this K-half

    // staging: round q (0..3) -> LDS byte q*4096 + tid*16
    //   q<2: A (P rows), ks = q*2 + (tid>>7); q>=2: B (S rows)
    const char* gsrc[4];
#pragma unroll
    for (int q = 0; q < 4; ++q) {
        const int ks = (q & 1) * 2 + (tid >> 7);
        const int row = tid & 127;
        gsrc[q] = (q < 2)
            ? (const char*)P + ((size_t)(kc + ks) * 2048 + bBase + row) * 16
            : (const char*)S + ((size_t)(kc + ks) * 2048 + oBase + row) * 16;
    }

#define RBF_STAGE(ST) do {                                                    \
    const size_t go_ = (size_t)(ST) * STEP_B;                                 \
    char* d_ = &sAB[(ST) & 3][0];                                             \
    gld16(gsrc[0] + go_, d_ + 0    + tid * 16);                               \
    gld16(gsrc[1] + go_, d_ + 4096 + tid * 16);                               \
    gld16(gsrc[2] + go_, d_ + 8192  + tid * 16);                              \
    gld16(gsrc[3] + go_, d_ + 12288 + tid * 16);                              \
} while (0)

    RBF_STAGE(0);
    RBF_STAGE(1);

    const f32x16 zz = {0.f,0.f,0.f,0.f,0.f,0.f,0.f,0.f,
                       0.f,0.f,0.f,0.f,0.f,0.f,0.f,0.f};
    f32x16 acc00 = zz, acc01 = zz, acc10 = zz, acc11 = zz;

    const int aoff = (wr * 64 + cl) * 16;          // + ks*2048 (+512 for +32)
    const int boff = 8192 + (wc * 64 + cl) * 16;

#pragma unroll 1
    for (int st = 0; st < K_STEPS; ++st) {
        if (st + 2 < K_STEPS) {
            RBF_STAGE(st + 2);
            asm volatile("s_waitcnt vmcnt(8)" ::: "memory");
        } else if (st + 1 < K_STEPS) {
            asm volatile("s_waitcnt vmcnt(4)" ::: "memory");
        } else {
            asm volatile("s_waitcnt vmcnt(0)" ::: "memory");
        }
        __builtin_amdgcn_s_barrier();
        __builtin_amdgcn_sched_barrier(0);
        const char* bp = &sAB[st & 3][0];

        __builtin_amdgcn_s_setprio(1);
#pragma unroll
        for (int s = 0; s < 2; ++s) {
            const int kso = (s * 2 + h) * 2048;
            const bf16x8 a0 = *(const bf16x8*)(bp + kso + aoff);
            const bf16x8 a1 = *(const bf16x8*)(bp + kso + aoff + 512);
            const bf16x8 b0 = *(const bf16x8*)(bp + kso + boff);
            const bf16x8 b1 = *(const bf16x8*)(bp + kso + boff + 512);
            acc00 = __builtin_amdgcn_mfma_f32_32x32x16_bf16(a0, b0, acc00, 0, 0, 0);
            acc01 = __builtin_amdgcn_mfma_f32_32x32x16_bf16(a0, b1, acc01, 0, 0, 0);
            acc10 = __builtin_amdgcn_mfma_f32_32x32x16_bf16(a1, b0, acc10, 0, 0, 0);
            acc11 = __builtin_amdgcn_mfma_f32_32x32x16_bf16(a1, b1, acc11, 0, 0, 0);
        }
        __builtin_amdgcn_s_setprio(0);
    }
#undef RBF_STAGE

    float* Cp = Cpart + (size_t)kh * O_N * B_N;
#pragma unroll
    for (int r = 0; r < 16; ++r) {
        const int row32 = (r & 3) + 8 * (r >> 2) + 4 * h;
        const size_t r0 = (size_t)(bBase + wr * 64 + row32) * O_N;
        const size_t r1 = (size_t)(bBase + wr * 64 + 32 + row32) * O_N;
        const int c0 = oBase + wc * 64 + cl;
        const int c1 = oBase + wc * 64 + 32 + cl;
        Cp[r0 + c0] = acc00[r];
        Cp[r0 + c1] = acc01[r];
        Cp[r1 + c0] = acc10[r];
        Cp[r1 + c1] = acc11[r];
    }
}

// ---------------------------------------------------------------------------
// reduce: out = exp(-(C0+C1)/2), pure streaming.
// ---------------------------------------------------------------------------
__global__ __launch_bounds__(256) void rbf_reduce(
    const float* __restrict__ C0, const float* __restrict__ C1,
    float* __restrict__ out)
{
    const size_t base = ((size_t)blockIdx.x * 256 + threadIdx.x) * 8;
#pragma unroll
    for (int q = 0; q < 2; ++q) {
        const size_t i = base + q * 4;
        const f32x4 a = *(const f32x4*)(C0 + i);
        const f32x4 b = *(const f32x4*)(C1 + i);
        f32x4 r;
#pragma unroll
        for (int e = 0; e < 4; ++e)
            r[e] = exp2f((a[e] + b[e]) * -0.72134752044448170368f);
        *(f32x4*)(out + i) = r;
    }
}

extern "C" void kernel_launch(void* const* d_in, const int* in_sizes, int n_in,
                              void* d_out, int out_size, void* d_ws, size_t ws_size,
                              hipStream_t stream)
{
    const float* x = (const float*)d_in[0];
    const float* means = (const float*)d_in[1];
    const float* inv = (const float*)d_in[2];
    float* out = (float*)d_out;

    const size_t SZ = (size_t)O_N * K_TOT * sizeof(__bf16);      // 9.44 MB
    const size_t CZ = (size_t)O_N * B_N * sizeof(float);         // 16.78 MB
    __bf16* St  = (__bf16*)d_ws;
    __bf16* Pt  = (__bf16*)((char*)d_ws + SZ);
    __bf16* Srm = (__bf16*)((char*)d_ws + 2 * SZ);
    float*  C0  = (float*)((char*)d_ws + 3 * SZ);
    float*  C1  = (float*)((char*)d_ws + 3 * SZ + CZ);

    rbf_prepA<<<dim3(O_N + 256), dim3(256), 0, stream>>>(inv, means, x, Srm, Pt);
    rbf_prepB<<<dim3(128), dim3(256), 0, stream>>>(Srm, St);
    rbf_gemm_sk<<<dim3(512), dim3(256), 0, stream>>>(Pt, St, C0);
    rbf_reduce<<<dim3(2048), dim3(256), 0, stream>>>(C0, C1, out);

    (void)in_sizes; (void)n_in; (void)out_size; (void)ws_size;
}